// Round 1
// baseline (142.989 us; speedup 1.0000x reference)
//
#include <hip/hip_runtime.h>
#include <hip/hip_bf16.h>
#include <stdint.h>

using bf16x8 = __attribute__((ext_vector_type(8))) short;
using f32x4  = __attribute__((ext_vector_type(4))) float;

#define N_NODES  50000
#define K1       768
#define D1       512
#define NPAIR    16384
#define NOUT     97
#define NOUT_PAD 112

__device__ __forceinline__ uint16_t f2bf(float f) {
    uint32_t u = __builtin_bit_cast(uint32_t, f);
    return (uint16_t)((u + 0x7fffu + ((u >> 16) & 1u)) >> 16);  // RNE
}

// ---- convert: W1[768][512] -> W1t bf16 [512][768]; Wp[1024][97] -> Wpt bf16 [112][1024] (zero-pad) ----
__global__ void k_convert(const float* __restrict__ W1, const float* __restrict__ Wp,
                          uint16_t* __restrict__ W1t, uint16_t* __restrict__ Wpt) {
    int idx = blockIdx.x * 256 + threadIdx.x;
    const int n1 = D1 * K1;
    if (idx < n1) {
        int c = idx / K1, k = idx - c * K1;
        W1t[idx] = f2bf(W1[k * D1 + c]);
    } else {
        int j = idx - n1;
        if (j < NOUT_PAD * 1024) {
            int c = j >> 10, k = j & 1023;
            Wpt[j] = (c < NOUT) ? f2bf(Wp[k * NOUT + c]) : (uint16_t)0;
        }
    }
}

// ---- GEMM1: H[50000][512] = relu(A[50000][768] @ W1 + b1), bf16 MFMA, 128x128 tile ----
__global__ __launch_bounds__(256) void k_gemm1(const float* __restrict__ A,
        const uint16_t* __restrict__ W1t, const float* __restrict__ bias1,
        uint16_t* __restrict__ H) {
    __shared__ uint16_t lds_a[128][40];   // +8 pad: ~2-way bank aliasing only
    __shared__ uint16_t lds_b[128][40];
    const int t = threadIdx.x;
    const int lane = t & 63, wave = t >> 6;
    const int wm = wave >> 1, wn = wave & 1;
    const int cl = lane & 15, kh = lane >> 4;
    const int bx = blockIdx.x;
    const int m0 = (bx >> 2) * 128, n0 = (bx & 3) * 128;  // ntile fastest -> A-tile L2 reuse

    f32x4 acc[4][4];
    const f32x4 z = {0.f, 0.f, 0.f, 0.f};
    #pragma unroll
    for (int m = 0; m < 4; ++m)
        #pragma unroll
        for (int n = 0; n < 4; ++n) acc[m][n] = z;

    const int srow = t >> 1, shalf = t & 1;
    int grow = m0 + srow; if (grow >= N_NODES) grow = N_NODES - 1;  // clamp tail tile
    const float*    asrc = A   + (size_t)grow * K1 + shalf * 16;
    const uint16_t* bsrc = W1t + (size_t)(n0 + srow) * K1 + shalf * 16;
    uint16_t* adst = &lds_a[srow][shalf * 16];
    uint16_t* bdst = &lds_b[srow][shalf * 16];

    for (int kt = 0; kt < K1 / 32; ++kt) {
        const int k0 = kt * 32;
        // issue global loads before the barrier (overlap with other waves' tail)
        const float4* ap = (const float4*)(asrc + k0);
        float4 f0 = ap[0], f1 = ap[1], f2 = ap[2], f3 = ap[3];
        const uint4* bp4 = (const uint4*)(bsrc + k0);
        uint4 b0 = bp4[0], b1 = bp4[1];
        uint16_t va[16];
        va[0]=f2bf(f0.x); va[1]=f2bf(f0.y); va[2]=f2bf(f0.z); va[3]=f2bf(f0.w);
        va[4]=f2bf(f1.x); va[5]=f2bf(f1.y); va[6]=f2bf(f1.z); va[7]=f2bf(f1.w);
        va[8]=f2bf(f2.x); va[9]=f2bf(f2.y); va[10]=f2bf(f2.z); va[11]=f2bf(f2.w);
        va[12]=f2bf(f3.x); va[13]=f2bf(f3.y); va[14]=f2bf(f3.z); va[15]=f2bf(f3.w);
        __syncthreads();                 // previous tile's reads done
        ((uint4*)adst)[0] = *(uint4*)&va[0];
        ((uint4*)adst)[1] = *(uint4*)&va[8];
        ((uint4*)bdst)[0] = b0;
        ((uint4*)bdst)[1] = b1;
        __syncthreads();                 // tile staged

        bf16x8 af[4], bfr[4];
        #pragma unroll
        for (int m = 0; m < 4; ++m)
            af[m] = *(const bf16x8*)&lds_a[wm*64 + m*16 + cl][kh*8];
        #pragma unroll
        for (int n = 0; n < 4; ++n)
            bfr[n] = *(const bf16x8*)&lds_b[wn*64 + n*16 + cl][kh*8];
        #pragma unroll
        for (int m = 0; m < 4; ++m)
            #pragma unroll
            for (int n = 0; n < 4; ++n)
                acc[m][n] = __builtin_amdgcn_mfma_f32_16x16x32_bf16(af[m], bfr[n], acc[m][n], 0, 0, 0);
    }

    // epilogue: +bias, relu, bf16 store.  C layout: col = lane&15, row = (lane>>4)*4 + r
    float bv[4]; int bcol[4];
    #pragma unroll
    for (int n = 0; n < 4; ++n) { bcol[n] = n0 + wn*64 + n*16 + cl; bv[n] = bias1[bcol[n]]; }
    #pragma unroll
    for (int m = 0; m < 4; ++m) {
        int rbase = m0 + wm*64 + m*16 + kh*4;
        #pragma unroll
        for (int r = 0; r < 4; ++r) {
            int row = rbase + r;
            if (row < N_NODES) {
                #pragma unroll
                for (int n = 0; n < 4; ++n) {
                    float v = acc[m][n][r] + bv[n];
                    H[(size_t)row * D1 + bcol[n]] = f2bf(fmaxf(v, 0.f));
                }
            }
        }
    }
}

// ---- GEMM2: out[16384][97] = concat(H[head], H[tail]) @ Wp + bp ----
__global__ __launch_bounds__(256) void k_gemm2(const uint16_t* __restrict__ H,
        const uint16_t* __restrict__ Wpt, const float* __restrict__ bp,
        const int* __restrict__ head, const int* __restrict__ tail,
        float* __restrict__ out) {
    __shared__ uint16_t lds_w[NOUT_PAD][40];
    const int t = threadIdx.x;
    const int lane = t & 63, wave = t >> 6;
    const int cl = lane & 15, kh = lane >> 4;
    const int rowbase = blockIdx.x * 64 + wave * 16;
    const int i_l = rowbase + cl;
    const int nodeH = head[i_l], nodeT = tail[i_l];
    const uint16_t* hH = H + (size_t)nodeH * D1 + kh * 8;
    const uint16_t* hT = H + (size_t)nodeT * D1 + kh * 8;

    f32x4 acc[7];
    const f32x4 z = {0.f, 0.f, 0.f, 0.f};
    #pragma unroll
    for (int n = 0; n < 7; ++n) acc[n] = z;

    const int wrow = t >> 1, whalf = t & 1;
    const uint16_t* wsrc = Wpt + (size_t)wrow * 1024 + whalf * 16;
    uint16_t* wdst = &lds_w[wrow][whalf * 16];

    for (int kb = 0; kb < 32; ++kb) {
        uint4 w0 = {0,0,0,0}, w1 = {0,0,0,0};
        if (t < 224) {
            const uint4* wp4 = (const uint4*)(wsrc + kb * 32);
            w0 = wp4[0]; w1 = wp4[1];
        }
        // k < 512 -> head half, else tail half (clean split at kb==16)
        bf16x8 af = (kb < 16) ? *(const bf16x8*)(hH + kb * 32)
                              : *(const bf16x8*)(hT + (kb - 16) * 32);
        __syncthreads();
        if (t < 224) { ((uint4*)wdst)[0] = w0; ((uint4*)wdst)[1] = w1; }
        __syncthreads();
        #pragma unroll
        for (int n = 0; n < 7; ++n) {
            bf16x8 bfr = *(const bf16x8*)&lds_w[n*16 + cl][kh*8];
            acc[n] = __builtin_amdgcn_mfma_f32_16x16x32_bf16(af, bfr, acc[n], 0, 0, 0);
        }
    }
    #pragma unroll
    for (int n = 0; n < 7; ++n) {
        int col = n * 16 + cl;
        if (col < NOUT) {
            float bb = bp[col];
            #pragma unroll
            for (int r = 0; r < 4; ++r) {
                int i = rowbase + kh * 4 + r;
                out[(size_t)i * NOUT + col] = acc[n][r] + bb;
            }
        }
    }
}

extern "C" void kernel_launch(void* const* d_in, const int* in_sizes, int n_in,
                              void* d_out, int out_size, void* d_ws, size_t ws_size,
                              hipStream_t stream) {
    const float* node_features = (const float*)d_in[0];
    // d_in[1] = edge_features (unused: message passing is an exact identity)
    const float* W1   = (const float*)d_in[2];
    const float* b1   = (const float*)d_in[3];
    const float* Wp   = (const float*)d_in[4];
    const float* bp   = (const float*)d_in[5];
    // d_in[6] = src (unused), d_in[7] = dst (unused)
    const int* head   = (const int*)d_in[8];
    const int* tail   = (const int*)d_in[9];
    float* out = (float*)d_out;

    char* ws = (char*)d_ws;
    uint16_t* H   = (uint16_t*)ws;                                           // 51,200,000 B
    uint16_t* W1t = (uint16_t*)(ws + (size_t)N_NODES * D1 * 2);              //    786,432 B
    uint16_t* Wpt = (uint16_t*)(ws + (size_t)N_NODES * D1 * 2 + (size_t)D1 * K1 * 2);  // 229,376 B

    const int convN = D1 * K1 + NOUT_PAD * 1024;
    k_convert<<<(convN + 255) / 256, 256, 0, stream>>>(W1, Wp, W1t, Wpt);

    const int mtiles = (N_NODES + 127) / 128;   // 391
    k_gemm1<<<mtiles * 4, 256, 0, stream>>>(node_features, W1t, b1, H);

    k_gemm2<<<NPAIR / 64, 256, 0, stream>>>(H, Wpt, bp, head, tail, out);
}